// Round 1
// baseline (316.600 us; speedup 1.0000x reference)
//
#include <hip/hip_runtime.h>
#include <math.h>

#define N_NODES 50000
#define N_EDGES 800000
#define CH      128     // in/out channels
#define KDIM    256     // 2*CH

// ---------------- ws layout (byte offsets, all 256B aligned) ----------------
// neigh : 0          float[50000*128]   25,600,000 B
// degcnt: 25,600,000 int[50000]
// cursor: 25,800,192 int[50000]
// offs  : 26,000,384 int[50001]
// col   : 26,200,832 int[800000]
// total ≈ 29.4 MB

__global__ void k_zero_counts(int* __restrict__ degcnt, int* __restrict__ cursor) {
  int i = blockIdx.x * blockDim.x + threadIdx.x;
  if (i < N_NODES) { degcnt[i] = 0; cursor[i] = 0; }
}

__global__ void k_degree(const int* __restrict__ dst, int* __restrict__ degcnt) {
  int e = blockIdx.x * blockDim.x + threadIdx.x;
  if (e < N_EDGES) atomicAdd(&degcnt[dst[e]], 1);
}

// single-block scan: wave-level shfl scan + cross-wave LDS, 4 syncs/chunk
__global__ void k_scan(const int* __restrict__ degcnt, int* __restrict__ offs) {
  __shared__ int wsum[16];
  __shared__ int s_run;
  int tid = threadIdx.x;            // 1024 threads
  int lane = tid & 63, wid = tid >> 6;
  if (tid == 0) s_run = 0;
  __syncthreads();
  for (int base = 0; base < N_NODES; base += 1024) {
    int i = base + tid;
    int v = (i < N_NODES) ? degcnt[i] : 0;
    int s = v;
    #pragma unroll
    for (int off = 1; off < 64; off <<= 1) {
      int t = __shfl_up(s, off, 64);
      if (lane >= off) s += t;
    }
    if (lane == 63) wsum[wid] = s;
    __syncthreads();
    if (wid == 0 && lane < 16) {
      int w = wsum[lane];
      #pragma unroll
      for (int off = 1; off < 16; off <<= 1) {
        int t = __shfl_up(w, off, 64);
        if (lane >= off) w += t;
      }
      wsum[lane] = w;
    }
    __syncthreads();
    int wbase = (wid == 0) ? 0 : wsum[wid - 1];
    int run = s_run;
    if (i < N_NODES) offs[i] = run + wbase + s - v;   // exclusive
    __syncthreads();
    if (tid == 1023) s_run = run + wsum[15];
    __syncthreads();
  }
  if (tid == 0) offs[N_NODES] = s_run;
}

__global__ void k_fill(const int* __restrict__ src, const int* __restrict__ dst,
                       const int* __restrict__ offs, int* __restrict__ cursor,
                       int* __restrict__ col) {
  int e = blockIdx.x * blockDim.x + threadIdx.x;
  if (e < N_EDGES) {
    int d = dst[e];
    int p = atomicAdd(&cursor[d], 1);
    col[offs[d] + p] = src[e];
  }
}

// one wave per node: sum x[src] rows (float2/lane = 512B/row coalesced), mean
__global__ void k_aggregate(const float* __restrict__ x, const int* __restrict__ offs,
                            const int* __restrict__ col, float* __restrict__ neigh) {
  int gtid = blockIdx.x * blockDim.x + threadIdx.x;
  int node = gtid >> 6;
  int lane = threadIdx.x & 63;
  if (node >= N_NODES) return;
  int beg = offs[node], end = offs[node + 1];
  const float2* xp = reinterpret_cast<const float2*>(x);
  float2 acc = make_float2(0.f, 0.f);
  int e = beg;
  for (; e + 1 < end; e += 2) {           // 2-edge unroll for MLP
    int s0 = col[e], s1 = col[e + 1];
    float2 v0 = xp[(size_t)s0 * 64 + lane];
    float2 v1 = xp[(size_t)s1 * 64 + lane];
    acc.x += v0.x; acc.y += v0.y;
    acc.x += v1.x; acc.y += v1.y;
  }
  if (e < end) {
    int s0 = col[e];
    float2 v0 = xp[(size_t)s0 * 64 + lane];
    acc.x += v0.x; acc.y += v0.y;
  }
  float inv = 1.0f / fmaxf((float)(end - beg), 1.0f);
  reinterpret_cast<float2*>(neigh)[(size_t)node * 64 + lane] =
      make_float2(acc.x * inv, acc.y * inv);
}

// out = [x | neigh] @ W^T + b, then row L2-normalize. 128-node tile, 256 thr,
// 8x8 micro-tile, KC=32 LDS chunks, XOR-swizzled float4 LDS reads.
__global__ __launch_bounds__(256) void k_gemm_norm(
    const float* __restrict__ x, const float* __restrict__ neigh,
    const float* __restrict__ W, const float* __restrict__ bias,
    float* __restrict__ out) {
  __shared__ float hs[128][32];   // hs[row][k ^ swz(row)]
  __shared__ float Ws[128][32];   // Ws[ch][k ^ swz(ch)]
  int tid = threadIdx.x;
  int tx = tid & 15;              // channel group: ch = tx*8 + j
  int ty = tid >> 4;              // node group:    node = ty*8 + i
  int node0 = blockIdx.x * 128;

  float acc[8][8];
  #pragma unroll
  for (int i = 0; i < 8; ++i)
    #pragma unroll
    for (int j = 0; j < 8; ++j) acc[i][j] = 0.f;

  for (int kb = 0; kb < KDIM; kb += 32) {
    const float* srcp = (kb < CH) ? x : neigh;
    int koff = kb & (CH - 1);
    // stage h tile: 128 rows x 32 k
    #pragma unroll
    for (int jj = 0; jj < 4; ++jj) {
      int idx = tid + 256 * jj;          // 0..1023
      int row = idx >> 3;
      int c4g = (idx & 7) * 4;
      int swz = ((row >> 3) & 7) * 4;
      int node = node0 + row;
      if (node >= N_NODES) node = N_NODES - 1;
      float4 v = *reinterpret_cast<const float4*>(&srcp[(size_t)node * CH + koff + c4g]);
      *reinterpret_cast<float4*>(&hs[row][c4g ^ swz]) = v;
    }
    // stage W tile: 128 ch x 32 k
    #pragma unroll
    for (int jj = 0; jj < 4; ++jj) {
      int idx = tid + 256 * jj;
      int ch = idx >> 3;
      int c4g = (idx & 7) * 4;
      int swz = ((ch >> 3) & 7) * 4;
      float4 v = *reinterpret_cast<const float4*>(&W[(size_t)ch * KDIM + kb + c4g]);
      *reinterpret_cast<float4*>(&Ws[ch][c4g ^ swz]) = v;
    }
    __syncthreads();
    int hswz = ((ty & 7) * 4);
    int wswz = ((tx & 7) * 4);
    #pragma unroll
    for (int k4 = 0; k4 < 32; k4 += 4) {
      float4 wv[8];
      #pragma unroll
      for (int j = 0; j < 8; ++j)
        wv[j] = *reinterpret_cast<const float4*>(&Ws[tx * 8 + j][k4 ^ wswz]);
      #pragma unroll
      for (int i = 0; i < 8; ++i) {
        float4 hv = *reinterpret_cast<const float4*>(&hs[ty * 8 + i][k4 ^ hswz]);
        #pragma unroll
        for (int j = 0; j < 8; ++j) {
          acc[i][j] += hv.x * wv[j].x;
          acc[i][j] += hv.y * wv[j].y;
          acc[i][j] += hv.z * wv[j].z;
          acc[i][j] += hv.w * wv[j].w;
        }
      }
    }
    __syncthreads();
  }

  float bv[8];
  #pragma unroll
  for (int j = 0; j < 8; ++j) bv[j] = bias[tx * 8 + j];

  #pragma unroll
  for (int i = 0; i < 8; ++i) {
    int node = node0 + ty * 8 + i;
    float o[8];
    float s = 0.f;
    #pragma unroll
    for (int j = 0; j < 8; ++j) { o[j] = acc[i][j] + bv[j]; s += o[j] * o[j]; }
    #pragma unroll
    for (int m = 1; m < 16; m <<= 1) s += __shfl_xor(s, m, 64);  // 16-lane row reduce
    float inv = 1.0f / fmaxf(sqrtf(s), 1e-12f);
    if (node < N_NODES) {
      float4 v0 = make_float4(o[0] * inv, o[1] * inv, o[2] * inv, o[3] * inv);
      float4 v1 = make_float4(o[4] * inv, o[5] * inv, o[6] * inv, o[7] * inv);
      *reinterpret_cast<float4*>(&out[(size_t)node * CH + tx * 8]) = v0;
      *reinterpret_cast<float4*>(&out[(size_t)node * CH + tx * 8 + 4]) = v1;
    }
  }
}

extern "C" void kernel_launch(void* const* d_in, const int* in_sizes, int n_in,
                              void* d_out, int out_size, void* d_ws, size_t ws_size,
                              hipStream_t stream) {
  const float* x  = (const float*)d_in[0];
  const int*   ei = (const int*)d_in[1];   // [2, E]: first E = src, next E = dst
  const float* W  = (const float*)d_in[2];
  const float* b  = (const float*)d_in[3];
  float* out = (float*)d_out;

  char* ws = (char*)d_ws;
  float* neigh = (float*)(ws + 0);
  int* degcnt  = (int*)(ws + 25600000);
  int* cursor  = (int*)(ws + 25800192);
  int* offs    = (int*)(ws + 26000384);
  int* col     = (int*)(ws + 26200832);
  const int* src = ei;
  const int* dst = ei + N_EDGES;

  k_zero_counts<<<(N_NODES + 255) / 256, 256, 0, stream>>>(degcnt, cursor);
  k_degree<<<(N_EDGES + 255) / 256, 256, 0, stream>>>(dst, degcnt);
  k_scan<<<1, 1024, 0, stream>>>(degcnt, offs);
  k_fill<<<(N_EDGES + 255) / 256, 256, 0, stream>>>(src, dst, offs, cursor, col);
  k_aggregate<<<((size_t)N_NODES * 64 + 255) / 256, 256, 0, stream>>>(x, offs, col, neigh);
  k_gemm_norm<<<(N_NODES + 127) / 128, 256, 0, stream>>>(x, neigh, W, b, out);
}